// Round 12
// baseline (2153.891 us; speedup 1.0000x reference)
//
#include <hip/hip_runtime.h>

// LSTM B=512, T=512, H=256. Round 12 = r10 minus the copier phase.
// r10 chain (~4400 cyc exposed): spin -> copier LLC read -> LDS scatter ->
// barrier -> ... -> block barrier -> flag. r11 proved stagger-hiding works but
// duplicating the LDS weight stream costs more than it saves. Here the chain
// itself is shortened on r10's 128-block structure:
//  - publish h in [m][hl] layout -> consumer lane's A-frag = ONE 16-B LLC load
//    (copier phase, h_full LDS, its bank conflicts, and one barrier deleted)
//  - per-wave flags + wave-local vmcnt drain -> no block barrier before flag
//  - A-loads overlap the 128 KB/step weight ds_read stream (the new floor)
// 128 blocks x 512 thr; group bid>>2 owns 16 batches; sub owns 64 h-cols;
// weights 128 KB LDS-resident. Wave (c=w&3, kh=w>>2): 4 gate-tiles x 4 kt.
// Safety: flag[M]=t+1 => M's step-t tile reads done (data-dep + drain); any
// publish at t+1 is after b1 which joins waves that spun ALL subs >= t+1 =>
// parity overwrite-before-read impossible. 128 blocks co-resident (1/CU).
// MFMA f32_16x16x32_f16: A=h[m=l16][k=quad*8+j], B=W[k][n=l16], D[m=quad*4+r][n].
// Weights prescaled by -log2e (i,f,o) / +2log2e (g).

typedef _Float16 half8 __attribute__((ext_vector_type(8)));
typedef float f32x4 __attribute__((ext_vector_type(4)));

constexpr int kT = 512;
constexpr float kLog2e = 1.44269504088896340736f;

#define ATL(p)    __hip_atomic_load((p), __ATOMIC_RELAXED, __HIP_MEMORY_SCOPE_AGENT)
#define ATS(p, v) __hip_atomic_store((p), (v), __ATOMIC_RELAXED, __HIP_MEMORY_SCOPE_AGENT)

// ws layout (bytes):
//   [0, 524288)         weight fragments fp16: frag (sub,c,g,kt) at half8 idx
//                       (sub*128 + (c*4+g)*8 + kt)*64 + lane
//   [524288, 1048576)   gbuf: tile(bid,par) 2 KB at +(bid*2+par)*2048,
//                       layout [m 0..15][hl 0..63] u16
//   [1048576, 1050624)  flags int[32][16]  (grp, sub*4+c)
//   [1050624, 1058816)  pbuf float[128][16]
__global__ void prep_weights(const float* __restrict__ W_hh, _Float16* __restrict__ ws)
{
    int gid = blockIdx.x * blockDim.x + threadIdx.x;  // 0..32767, one half8 each
    int lane = gid & 63;
    int f = (gid >> 6) & 127;
    int sub = gid >> 13;
    int kt = f & 7, g = (f >> 3) & 3, c = f >> 5;
    int R = g * 256 + sub * 64 + c * 16 + (lane & 15);
    int k = kt * 32 + (lane >> 4) * 8;
    float s = (g == 2) ? 2.0f * kLog2e : -kLog2e;
    const float* src = W_hh + R * 256 + k;
    half8 v;
    #pragma unroll
    for (int j = 0; j < 8; ++j) v[j] = (_Float16)(src[j] * s);
    reinterpret_cast<half8*>(ws)[gid] = v;
}

__device__ __forceinline__ f32x4 mfma16(half8 a, half8 b, f32x4 c) {
    return __builtin_amdgcn_mfma_f32_16x16x32_f16(a, b, c, 0, 0, 0);
}

__global__ __launch_bounds__(512, 2)
void lstm_main(const float* __restrict__ ts,
               const float* __restrict__ W_ih,
               const float* __restrict__ b_ih,
               const float* __restrict__ b_hh,
               const float* __restrict__ W_out,
               const _Float16* __restrict__ wfrag,
               unsigned short* __restrict__ gb,
               int* __restrict__ flags,
               float* __restrict__ pbuf)
{
    __shared__ __align__(16) _Float16 wlds[65536];        // 128 KB weights
    __shared__ __align__(16) float pacc1[4][4][16][20];   // 20 KB (kh=1 partials)
    __shared__ float red[4][16];

    const int tid  = threadIdx.x;
    const int w    = tid >> 6;
    const int lane = tid & 63;
    const int l16  = lane & 15;
    const int quad = lane >> 4;
    const int bid  = blockIdx.x;
    const int sub  = bid & 3;
    const int grp  = bid >> 2;
    const int b0   = grp * 16;
    const int c    = w & 3;       // column-group 0..3
    const int kh   = w >> 2;      // K-half 0..1

    const half8* wf8 = reinterpret_cast<const half8*>(wfrag) + sub * 8192;
    half8* wl8 = reinterpret_cast<half8*>(wlds);
    for (int i = tid; i < 8192; i += 512) wl8[i] = wf8[i];

    float wih[4], bias[4];
    if (w < 4) {
        #pragma unroll
        for (int g = 0; g < 4; ++g) {
            int R = g * 256 + sub * 64 + c * 16 + l16;
            float s = (g == 2) ? 2.0f * kLog2e : -kLog2e;
            wih[g]  = W_ih[R] * s;
            bias[g] = (b_ih[R] + b_hh[R]) * s;
        }
    }

    const unsigned long long* gb64 = reinterpret_cast<const unsigned long long*>(gb);
    unsigned short* myt[2] = { gb + (bid * 2 + 0) * 1024, gb + (bid * 2 + 1) * 1024 };
    const int fbase = grp * 16;

    float cst[4]  = {0.f, 0.f, 0.f, 0.f};
    float oacc[4] = {0.f, 0.f, 0.f, 0.f};

    __syncthreads();

    for (int t = 0; t < kT; ++t) {
        const int wpar = t & 1, rp = (t + 1) & 1;

        // ---- spin on the 8 flags this wave's kt-range needs (subs 2kh, 2kh+1) ----
        if (t > 0) {
            const int myfl = fbase + kh * 8 + (lane & 7);
            for (;;) {
                int v = (lane < 8) ? ATL(&flags[myfl]) : t;
                if (__all(v >= t)) break;
                __builtin_amdgcn_s_sleep(2);
            }
            asm volatile("" ::: "memory");
        }

        // ---- A fragments: direct 16-B LLC loads from [m][hl] tiles ----
        half8 a[4];
        #pragma unroll
        for (int j = 0; j < 4; ++j) {
            int kt = kh * 4 + j;
            int s  = kt >> 1;
            const unsigned long long* tp = gb64 + ((grp * 4 + s) * 2 + rp) * 256;
            int ui = l16 * 16 + (kt & 1) * 8 + quad * 2;
            union { unsigned long long u[2]; half8 h; } cv;
            cv.u[0] = ATL(tp + ui);
            cv.u[1] = ATL(tp + ui + 1);
            a[j] = cv.h;
        }

        // prefetch nonlin operands early (VMEM overlaps MFMA/LDS)
        float tsv[4], wo = 0.f;
        if (w < 4) {
            #pragma unroll
            for (int r = 0; r < 4; ++r) tsv[r] = ts[(b0 + quad * 4 + r) * kT + t];
            wo = W_out[t * 256 + sub * 64 + c * 16 + l16];
        }

        // ---- MFMA: 4 gate-tiles x 4 kt, weights streamed from LDS ----
        f32x4 gacc[4];
        #pragma unroll
        for (int g = 0; g < 4; ++g) { f32x4 z = {0.f, 0.f, 0.f, 0.f}; gacc[g] = z; }
        #pragma unroll
        for (int j = 0; j < 4; ++j)
            #pragma unroll
            for (int g = 0; g < 4; ++g)
                gacc[g] = mfma16(a[j], wl8[(((c * 4 + g) * 8) + kh * 4 + j) * 64 + lane], gacc[g]);

        if (w >= 4) {
            #pragma unroll
            for (int g = 0; g < 4; ++g)
                *reinterpret_cast<f32x4*>(&pacc1[c][g][l16][quad * 4]) = gacc[g];
        }
        __syncthreads();   // b1: pacc visible to nonlin waves

        if (w < 4) {
            f32x4 p1[4];
            #pragma unroll
            for (int g = 0; g < 4; ++g)
                p1[g] = *reinterpret_cast<const f32x4*>(&pacc1[c][g][l16][quad * 4]);
            const int hl = c * 16 + l16;
            unsigned short* mt = myt[wpar];
            #pragma unroll
            for (int r = 0; r < 4; ++r) {
                float gi = gacc[0][r] + p1[0][r] + (tsv[r] * wih[0] + bias[0]);
                float gf = gacc[1][r] + p1[1][r] + (tsv[r] * wih[1] + bias[1]);
                float gg = gacc[2][r] + p1[2][r] + (tsv[r] * wih[2] + bias[2]);
                float go = gacc[3][r] + p1[3][r] + (tsv[r] * wih[3] + bias[3]);
                float I = __builtin_amdgcn_rcpf(1.0f + __builtin_amdgcn_exp2f(gi));
                float F = __builtin_amdgcn_rcpf(1.0f + __builtin_amdgcn_exp2f(gf));
                float G = 1.0f - 2.0f * __builtin_amdgcn_rcpf(1.0f + __builtin_amdgcn_exp2f(gg));
                float O = __builtin_amdgcn_rcpf(1.0f + __builtin_amdgcn_exp2f(go));
                float cn = F * cst[r] + I * G;
                cst[r] = cn;
                float tc = 1.0f - 2.0f * __builtin_amdgcn_rcpf(
                               1.0f + __builtin_amdgcn_exp2f(2.0f * kLog2e * cn));
                float hv = O * tc;
                oacc[r] += hv * wo;
                _Float16 h16 = (_Float16)hv;
                // publish [m][hl]: lanes of a quad-row write 16 contiguous u16
                ATS(&mt[(quad * 4 + r) * 64 + hl], __builtin_bit_cast(unsigned short, h16));
            }
            // wave-local drain, then this wave's flag — no block barrier on the chain
            asm volatile("s_waitcnt vmcnt(0)" ::: "memory");
            if (lane == 0) ATS(&flags[fbase + sub * 4 + c], t + 1);
        }
        __syncthreads();   // b2: protect pacc reuse next step
    }

    // ---- output partials: sum over cols (l16 lanes), then c-groups ----
    if (w < 4) {
        #pragma unroll
        for (int r = 0; r < 4; ++r) {
            float v = oacc[r];
            v += __shfl_xor(v, 1, 64);
            v += __shfl_xor(v, 2, 64);
            v += __shfl_xor(v, 4, 64);
            v += __shfl_xor(v, 8, 64);
            oacc[r] = v;
        }
        if (l16 == 0) {
            #pragma unroll
            for (int r = 0; r < 4; ++r) red[c][quad * 4 + r] = oacc[r];
        }
    }
    __syncthreads();
    if (tid < 16) {
        float s = 0.f;
        #pragma unroll
        for (int cc = 0; cc < 4; ++cc) s += red[cc][tid];
        pbuf[bid * 16 + tid] = s;
    }
}

__global__ void finalize(const float* __restrict__ pbuf,
                         const float* __restrict__ b_out,
                         float* __restrict__ out)
{
    int b = blockIdx.x * blockDim.x + threadIdx.x;   // 0..511
    int grp = b >> 4, m = b & 15;
    float s = b_out[0];
    #pragma unroll
    for (int s4 = 0; s4 < 4; ++s4) s += pbuf[((grp * 4 + s4) * 16) + m];
    out[b] = s;
}

extern "C" void kernel_launch(void* const* d_in, const int* in_sizes, int n_in,
                              void* d_out, int out_size, void* d_ws, size_t ws_size,
                              hipStream_t stream) {
    const float* ts    = (const float*)d_in[0];
    const float* W_ih  = (const float*)d_in[1];
    const float* W_hh  = (const float*)d_in[2];
    const float* b_ih  = (const float*)d_in[3];
    const float* b_hh  = (const float*)d_in[4];
    const float* W_out = (const float*)d_in[5];
    const float* b_out = (const float*)d_in[6];

    char* wsb = (char*)d_ws;
    _Float16*       wfrag = (_Float16*)wsb;
    unsigned short* gb    = (unsigned short*)(wsb + 524288);
    int*            flags = (int*)(wsb + 1048576);
    float*          pbuf  = (float*)(wsb + 1050624);

    // zero gbuf (t=0 reads parity-1 tiles as h_{-1}=0) + flags + pbuf
    hipMemsetAsync(wsb + 524288, 0, 524288 + 2048 + 8192, stream);
    prep_weights<<<128, 256, 0, stream>>>(W_hh, wfrag);
    lstm_main<<<128, 512, 0, stream>>>(ts, W_ih, b_ih, b_hh, W_out,
                                       wfrag, gb, flags, pbuf);
    finalize<<<1, 512, 0, stream>>>(pbuf, b_out, (float*)d_out);
}

// Round 13
// 1539.918 us; speedup vs baseline: 1.3987x; 1.3987x over previous
//
#include <hip/hip_runtime.h>

// LSTM B=512, T=512, H=256. Round 13 = r10 + three chain cuts.
// r10 step (7370 cyc): LLC chain ~2500 + LDS weight stream ~1550 (exposed) +
// 3 barriers + nonlin/scatter. r12 proved direct-LLC A-reads regress (4x LLC
// amplification); copier-into-LDS stays. Deltas here:
//  1. stage each wave's 16 weight b128 ds_reads BEFORE the spin window (addresses
//     are loop-invariant) -> LDS pipe streams under the LLC RT instead of after.
//  2. per-(block,c) flags: nonlin wave drains own vmcnt + stores flag; copier
//     thread polls the single flag covering its hl range (c_src = hl>>4).
//  3. end barrier deleted: A-reads drain at b1; pacc(t+1) writes gated by
//     b_copy(t+1); parity-tile safety: spin>=t at t => remote consumed t-2.
// 128 blocks x 512 thr; grp=bid>>2 owns 16 batches; sub=bid&3 owns 64 h-cols;
// weights 128 KB LDS. Wave (c=w&3, kh=w>>2): 4 gate-tiles x 4 kt.
// MFMA f32_16x16x32_f16: A=h[m=l16][k=quad*8+j], B=W[k][n=l16], D[m=quad*4+r][n].
// Weights prescaled by -log2e (i,f,o) / +2log2e (g).

typedef _Float16 half8 __attribute__((ext_vector_type(8)));
typedef float f32x4 __attribute__((ext_vector_type(4)));

constexpr int kT = 512;
constexpr int kHF = 264;   // h_full row stride (halves)
constexpr float kLog2e = 1.44269504088896340736f;

#define ATL(p)    __hip_atomic_load((p), __ATOMIC_RELAXED, __HIP_MEMORY_SCOPE_AGENT)
#define ATS(p, v) __hip_atomic_store((p), (v), __ATOMIC_RELAXED, __HIP_MEMORY_SCOPE_AGENT)

// ws layout (bytes):
//   [0, 524288)         weight fragments fp16: frag (sub,c,g,kt) at half8 idx
//                       (sub*128 + (c*4+g)*8 + kt)*64 + lane
//   [524288, 1048576)   gbuf: tile(bid,par) 2 KB at +(bid*2+par)*2048,
//                       layout [hl 0..63][m 0..15] u16 (u64 = [hl][4m])
//   [1048576, 1050624)  flags int[128][4]  (bid, c)
//   [1050624, 1058816)  pbuf float[128][16]
__global__ void prep_weights(const float* __restrict__ W_hh, _Float16* __restrict__ ws)
{
    int gid = blockIdx.x * blockDim.x + threadIdx.x;  // 0..32767, one half8 each
    int lane = gid & 63;
    int f = (gid >> 6) & 127;
    int sub = gid >> 13;
    int kt = f & 7, g = (f >> 3) & 3, c = f >> 5;
    int R = g * 256 + sub * 64 + c * 16 + (lane & 15);
    int k = kt * 32 + (lane >> 4) * 8;
    float s = (g == 2) ? 2.0f * kLog2e : -kLog2e;
    const float* src = W_hh + R * 256 + k;
    half8 v;
    #pragma unroll
    for (int j = 0; j < 8; ++j) v[j] = (_Float16)(src[j] * s);
    reinterpret_cast<half8*>(ws)[gid] = v;
}

__device__ __forceinline__ f32x4 mfma16(half8 a, half8 b, f32x4 c) {
    return __builtin_amdgcn_mfma_f32_16x16x32_f16(a, b, c, 0, 0, 0);
}

__global__ __launch_bounds__(512, 2)
void lstm_main(const float* __restrict__ ts,
               const float* __restrict__ W_ih,
               const float* __restrict__ b_ih,
               const float* __restrict__ b_hh,
               const float* __restrict__ W_out,
               const _Float16* __restrict__ wfrag,
               unsigned short* __restrict__ gb,
               int* __restrict__ flags,
               float* __restrict__ pbuf)
{
    __shared__ __align__(16) _Float16 wlds[65536];        // 128 KB weights
    __shared__ __align__(16) _Float16 h_full[16][kHF];    // 8448 B
    __shared__ __align__(16) float pacc1[4][4][16][20];   // 20 KB (kh=1 partials)
    __shared__ float red[4][16];

    const int tid  = threadIdx.x;
    const int w    = tid >> 6;
    const int lane = tid & 63;
    const int l16  = lane & 15;
    const int quad = lane >> 4;
    const int bid  = blockIdx.x;
    const int sub  = bid & 3;
    const int grp  = bid >> 2;
    const int b0   = grp * 16;
    const int c    = w & 3;       // column-group 0..3
    const int kh   = w >> 2;      // K-half 0..1

    const half8* wf8 = reinterpret_cast<const half8*>(wfrag) + sub * 8192;
    half8* wl8 = reinterpret_cast<half8*>(wlds);
    for (int i = tid; i < 8192; i += 512) wl8[i] = wf8[i];
    for (int i = tid; i < 16 * kHF; i += 512) (&h_full[0][0])[i] = (_Float16)0.0f;

    float wih[4], bias[4];
    if (w < 4) {
        #pragma unroll
        for (int g = 0; g < 4; ++g) {
            int R = g * 256 + sub * 64 + c * 16 + l16;
            float s = (g == 2) ? 2.0f * kLog2e : -kLog2e;
            wih[g]  = W_ih[R] * s;
            bias[g] = (b_ih[R] + b_hh[R]) * s;
        }
    }

    // copier mapping (r10): tid>=128 copies 16 B of partner tile psub
    const int cs    = tid >> 7;
    const int psub  = (sub + cs) & 3;
    const int pbid  = (grp << 2) | psub;
    const int i0    = (tid & 127) * 2;     // u64 index in tile
    const int chl   = i0 >> 2;             // hl 0..63
    const int cm0   = (i0 & 3) * 4;        // 0 or 8
    const int c_src = chl >> 4;            // which c-wave produces this hl
    const unsigned long long* gb64 = reinterpret_cast<const unsigned long long*>(gb);
    unsigned short* myt[2] = { gb + (bid * 2 + 0) * 1024, gb + (bid * 2 + 1) * 1024 };

    float cst[4]  = {0.f, 0.f, 0.f, 0.f};
    float oacc[4] = {0.f, 0.f, 0.f, 0.f};

    __syncthreads();

    for (int t = 0; t < kT; ++t) {
        const int wpar = t & 1, rp = (t + 1) & 1;

        // ---- (1) stage weights: 16 b128 ds_reads issued BEFORE the spin ----
        half8 wst[16];
        #pragma unroll
        for (int g = 0; g < 4; ++g)
            #pragma unroll
            for (int j = 0; j < 4; ++j)
                wst[g * 4 + j] = wl8[(((c * 4 + g) * 8) + kh * 4 + j) * 64 + lane];
        asm volatile("" ::: "memory");   // pin issue point above the spin

        // VMEM prefetch for nonlin (under the spin window too)
        float tsv[4], wo = 0.f;
        if (w < 4) {
            #pragma unroll
            for (int r = 0; r < 4; ++r) tsv[r] = ts[(b0 + quad * 4 + r) * kT + t];
            wo = W_out[t * 256 + sub * 64 + c * 16 + l16];
        }

        // ---- (2) copier: per-thread spin on the single flag for its hl ----
        if (cs >= 1) {
            if (t > 0) {
                while (ATL(&flags[pbid * 4 + c_src]) < t) __builtin_amdgcn_s_sleep(1);
                asm volatile("" ::: "memory");
            }
            const unsigned long long* pt = gb64 + (pbid * 2 + rp) * 256;
            unsigned long long d0 = ATL(pt + i0);
            unsigned long long d1 = ATL(pt + i0 + 1);
            union { unsigned long long u; unsigned short s[4]; } u0, u1;
            u0.u = d0; u1.u = d1;
            #pragma unroll
            for (int j = 0; j < 4; ++j) {
                reinterpret_cast<unsigned short*>(&h_full[cm0 + j][psub * 64 + chl])[0] = u0.s[j];
                reinterpret_cast<unsigned short*>(&h_full[cm0 + 4 + j][psub * 64 + chl])[0] = u1.s[j];
            }
        }
        __syncthreads();   // b_copy: h_full = full h_{t-1}

        // ---- A fragments + MFMA (weights already in wst) ----
        half8 a[4];
        #pragma unroll
        for (int j = 0; j < 4; ++j)
            a[j] = *reinterpret_cast<const half8*>(&h_full[l16][(kh * 4 + j) * 32 + quad * 8]);
        f32x4 gacc[4];
        #pragma unroll
        for (int g = 0; g < 4; ++g) { f32x4 z = {0.f, 0.f, 0.f, 0.f}; gacc[g] = z; }
        #pragma unroll
        for (int j = 0; j < 4; ++j)
            #pragma unroll
            for (int g = 0; g < 4; ++g)
                gacc[g] = mfma16(a[j], wst[g * 4 + j], gacc[g]);

        if (w >= 4) {
            #pragma unroll
            for (int g = 0; g < 4; ++g)
                *reinterpret_cast<f32x4*>(&pacc1[c][g][l16][quad * 4]) = gacc[g];
        }
        __syncthreads();   // b1: pacc visible; all A-reads drained

        if (w < 4) {
            f32x4 p1[4];
            #pragma unroll
            for (int g = 0; g < 4; ++g)
                p1[g] = *reinterpret_cast<const f32x4*>(&pacc1[c][g][l16][quad * 4]);
            const int hl = c * 16 + l16;
            const int hk = sub * 64 + hl;
            unsigned short* mt = myt[wpar];
            union { unsigned long long u; unsigned short s[4]; } hp;
            #pragma unroll
            for (int r = 0; r < 4; ++r) {
                float gi = gacc[0][r] + p1[0][r] + (tsv[r] * wih[0] + bias[0]);
                float gf = gacc[1][r] + p1[1][r] + (tsv[r] * wih[1] + bias[1]);
                float gg = gacc[2][r] + p1[2][r] + (tsv[r] * wih[2] + bias[2]);
                float go = gacc[3][r] + p1[3][r] + (tsv[r] * wih[3] + bias[3]);
                float I = __builtin_amdgcn_rcpf(1.0f + __builtin_amdgcn_exp2f(gi));
                float F = __builtin_amdgcn_rcpf(1.0f + __builtin_amdgcn_exp2f(gf));
                float G = 1.0f - 2.0f * __builtin_amdgcn_rcpf(1.0f + __builtin_amdgcn_exp2f(gg));
                float O = __builtin_amdgcn_rcpf(1.0f + __builtin_amdgcn_exp2f(go));
                float cn = F * cst[r] + I * G;
                cst[r] = cn;
                float tc = 1.0f - 2.0f * __builtin_amdgcn_rcpf(
                               1.0f + __builtin_amdgcn_exp2f(2.0f * kLog2e * cn));
                float hv = O * tc;
                oacc[r] += hv * wo;
                _Float16 h16 = (_Float16)hv;
                hp.s[r] = __builtin_bit_cast(unsigned short, h16);
                h_full[quad * 4 + r][hk] = h16;    // own-sub LDS copy for t+1
            }
            // publish [hl][m] u64 + wave-local drain + this wave's flag
            ATS((unsigned long long*)mt + (hl * 4 + quad), hp.u);
            asm volatile("s_waitcnt vmcnt(0)" ::: "memory");
            if (lane == 0) ATS(&flags[bid * 4 + c], t + 1);
        }
        // no end barrier: pacc(t+1) writes are gated by b_copy(t+1);
        // h_full scatter(t+1) is after b1(t) which drained all A-reads(t).
    }

    // ---- output partials: sum over cols (l16 lanes), then c-groups ----
    if (w < 4) {
        #pragma unroll
        for (int r = 0; r < 4; ++r) {
            float v = oacc[r];
            v += __shfl_xor(v, 1, 64);
            v += __shfl_xor(v, 2, 64);
            v += __shfl_xor(v, 4, 64);
            v += __shfl_xor(v, 8, 64);
            oacc[r] = v;
        }
        if (l16 == 0) {
            #pragma unroll
            for (int r = 0; r < 4; ++r) red[c][quad * 4 + r] = oacc[r];
        }
    }
    __syncthreads();
    if (tid < 16) {
        float s = 0.f;
        #pragma unroll
        for (int cc = 0; cc < 4; ++cc) s += red[cc][tid];
        pbuf[bid * 16 + tid] = s;
    }
}

__global__ void finalize(const float* __restrict__ pbuf,
                         const float* __restrict__ b_out,
                         float* __restrict__ out)
{
    int b = blockIdx.x * blockDim.x + threadIdx.x;   // 0..511
    int grp = b >> 4, m = b & 15;
    float s = b_out[0];
    #pragma unroll
    for (int s4 = 0; s4 < 4; ++s4) s += pbuf[((grp * 4 + s4) * 16) + m];
    out[b] = s;
}

extern "C" void kernel_launch(void* const* d_in, const int* in_sizes, int n_in,
                              void* d_out, int out_size, void* d_ws, size_t ws_size,
                              hipStream_t stream) {
    const float* ts    = (const float*)d_in[0];
    const float* W_ih  = (const float*)d_in[1];
    const float* W_hh  = (const float*)d_in[2];
    const float* b_ih  = (const float*)d_in[3];
    const float* b_hh  = (const float*)d_in[4];
    const float* W_out = (const float*)d_in[5];
    const float* b_out = (const float*)d_in[6];

    char* wsb = (char*)d_ws;
    _Float16*       wfrag = (_Float16*)wsb;
    unsigned short* gb    = (unsigned short*)(wsb + 524288);
    int*            flags = (int*)(wsb + 1048576);
    float*          pbuf  = (float*)(wsb + 1050624);

    // zero gbuf (t=0 reads parity-1 tiles as h_{-1}=0) + flags + pbuf
    hipMemsetAsync(wsb + 524288, 0, 524288 + 2048 + 8192, stream);
    prep_weights<<<128, 256, 0, stream>>>(W_hh, wfrag);
    lstm_main<<<128, 512, 0, stream>>>(ts, W_ih, b_ih, b_hh, W_out,
                                       wfrag, gb, flags, pbuf);
    finalize<<<1, 512, 0, stream>>>(pbuf, b_out, (float*)d_out);
}

// Round 14
// 1454.457 us; speedup vs baseline: 1.4809x; 1.0588x over previous
//
#include <hip/hip_runtime.h>

// LSTM B=512, T=512, H=256. Round 14 = r13 + half-reg weight tier + balanced nonlin.
// r13 post-mortem: wst staging sank (VGPR 88 unchanged) — empty clobber can't pin.
// Here: 8 of 16 frags per wave HOISTED OUT OF THE LOOP into 32 VGPRs with in-loop
// "+v" re-pin. Total live ~120 <= 128 cap -> no spill incentive (the one regime
// where r6-r9 showed pins hold). wlds halves to 64 KB (~775 cyc/step saved).
// Balanced nonlin: wave (c,kh) finalizes batch-rows kh*2+{0,1}; writes its other
// two rows' partials to pacc, reads partner's; both kh waves publish (u32) and
// own flag flags[bid*8+c*2+kh]; copier polls 2 flags. Halves serial nonlin VALU
// and publish tail; uses the formerly-idle half of the block.
// 128 blocks x 512 thr; grp=bid>>2 owns 16 batches; sub owns 64 h-cols.
// MFMA f32_16x16x32_f16: A=h[m=l16][k=quad*8+j], B=W[k][n=l16], D[m=quad*4+r][n].
// Weights prescaled by -log2e (i,f,o) / +2log2e (g).

typedef _Float16 half8 __attribute__((ext_vector_type(8)));
typedef float f32x4 __attribute__((ext_vector_type(4)));
typedef float f32x2 __attribute__((ext_vector_type(2)));

constexpr int kT = 512;
constexpr int kHF = 264;   // h_full row stride (halves)
constexpr float kLog2e = 1.44269504088896340736f;

#define ATL(p)    __hip_atomic_load((p), __ATOMIC_RELAXED, __HIP_MEMORY_SCOPE_AGENT)
#define ATS(p, v) __hip_atomic_store((p), (v), __ATOMIC_RELAXED, __HIP_MEMORY_SCOPE_AGENT)

// ws layout (bytes):
//   [0, 524288)         weight fragments fp16: frag (sub,c,g,kt) at half8 idx
//                       (sub*128 + (c*4+g)*8 + kt)*64 + lane
//   [524288, 1048576)   gbuf: tile(bid,par) 2 KB at +(bid*2+par)*2048, [hl][m] u16
//   [1048576, 1052672)  flags int[128][8]  (bid, c*2+kh)
//   [1052672, 1060864)  pbuf float[128][16]
__global__ void prep_weights(const float* __restrict__ W_hh, _Float16* __restrict__ ws)
{
    int gid = blockIdx.x * blockDim.x + threadIdx.x;  // 0..32767, one half8 each
    int lane = gid & 63;
    int f = (gid >> 6) & 127;
    int sub = gid >> 13;
    int kt = f & 7, g = (f >> 3) & 3, c = f >> 5;
    int R = g * 256 + sub * 64 + c * 16 + (lane & 15);
    int k = kt * 32 + (lane >> 4) * 8;
    float s = (g == 2) ? 2.0f * kLog2e : -kLog2e;
    const float* src = W_hh + R * 256 + k;
    half8 v;
    #pragma unroll
    for (int j = 0; j < 8; ++j) v[j] = (_Float16)(src[j] * s);
    reinterpret_cast<half8*>(ws)[gid] = v;
}

__device__ __forceinline__ f32x4 mfma16(half8 a, half8 b, f32x4 c) {
    return __builtin_amdgcn_mfma_f32_16x16x32_f16(a, b, c, 0, 0, 0);
}

__global__ __launch_bounds__(512, 2)
void lstm_main(const float* __restrict__ ts,
               const float* __restrict__ W_ih,
               const float* __restrict__ b_ih,
               const float* __restrict__ b_hh,
               const float* __restrict__ W_out,
               const _Float16* __restrict__ wfrag,
               unsigned short* __restrict__ gb,
               int* __restrict__ flags,
               float* __restrict__ pbuf)
{
    __shared__ __align__(16) _Float16 wlds[32768];        // 64 KB: j=2,3 frags
    __shared__ __align__(16) _Float16 h_full[16][kHF];    // 8448 B
    __shared__ __align__(16) float pacc1[4][2][4][16][10];// 20480 B, padded [10]
    __shared__ float red[4][16];

    const int tid  = threadIdx.x;
    const int w    = tid >> 6;
    const int lane = tid & 63;
    const int l16  = lane & 15;
    const int quad = lane >> 4;
    const int bid  = blockIdx.x;
    const int sub  = bid & 3;
    const int grp  = bid >> 2;
    const int b0   = grp * 16;
    const int c    = w & 3;       // column-group 0..3
    const int kh   = w >> 2;      // K-half 0..1

    const half8* wf8 = reinterpret_cast<const half8*>(wfrag) + sub * 8192;
    half8* wl8 = reinterpret_cast<half8*>(wlds);

    // stage LDS weight tier: frags (c,g,kh,jj) = src kt kh*4+2+jj
    for (int i = tid; i < 4096; i += 512) {
        int f = i >> 6, ln = i & 63;
        int jj = f & 1, kh_ = (f >> 1) & 1, g_ = (f >> 2) & 3, c_ = f >> 4;
        wl8[i] = wf8[(((c_ * 4 + g_) * 8) + kh_ * 4 + 2 + jj) * 64 + ln];
    }
    for (int i = tid; i < 16 * kHF; i += 512) (&h_full[0][0])[i] = (_Float16)0.0f;

    // ---- register weight tier: frags j=0,1 (kt = kh*4 + j), 32 VGPRs ----
    unsigned int wr_[8][4];
    #pragma unroll
    for (int g = 0; g < 4; ++g)
        #pragma unroll
        for (int jj = 0; jj < 2; ++jj) {
            uint4 v = *reinterpret_cast<const uint4*>(
                &wf8[(((c * 4 + g) * 8) + kh * 4 + jj) * 64 + lane]);
            int i = g * 2 + jj;
            wr_[i][0] = v.x; wr_[i][1] = v.y; wr_[i][2] = v.z; wr_[i][3] = v.w;
            asm volatile("" : "+v"(wr_[i][0]), "+v"(wr_[i][1]), "+v"(wr_[i][2]), "+v"(wr_[i][3]));
        }

    // per-col scalars (all waves do nonlin now)
    float wih[4], bias[4];
    #pragma unroll
    for (int g = 0; g < 4; ++g) {
        int R = g * 256 + sub * 64 + c * 16 + l16;
        float s = (g == 2) ? 2.0f * kLog2e : -kLog2e;
        wih[g]  = W_ih[R] * s;
        bias[g] = (b_ih[R] + b_hh[R]) * s;
    }

    // copier mapping (r13): tid>=128 copies 16 B of partner tile psub
    const int cs    = tid >> 7;
    const int psub  = (sub + cs) & 3;
    const int pbid  = (grp << 2) | psub;
    const int i0    = (tid & 127) * 2;
    const int chl   = i0 >> 2;
    const int cm0   = (i0 & 3) * 4;
    const int c_src = chl >> 4;
    const unsigned long long* gb64 = reinterpret_cast<const unsigned long long*>(gb);
    unsigned short* myt[2] = { gb + (bid * 2 + 0) * 1024, gb + (bid * 2 + 1) * 1024 };

    float cst[2]  = {0.f, 0.f};
    float oacc[2] = {0.f, 0.f};

    __syncthreads();

    for (int t = 0; t < kT; ++t) {
        const int wpar = t & 1, rp = (t + 1) & 1;

        // in-loop re-pin: under 128-reg budget -> allocator keeps them resident
        #pragma unroll
        for (int i = 0; i < 8; ++i)
            asm volatile("" : "+v"(wr_[i][0]), "+v"(wr_[i][1]), "+v"(wr_[i][2]), "+v"(wr_[i][3]));

        // nonlin VMEM prefetch (every wave: its 2 batch-rows)
        float tsv[2];
        #pragma unroll
        for (int rr = 0; rr < 2; ++rr)
            tsv[rr] = ts[(b0 + quad * 4 + kh * 2 + rr) * kT + t];
        float wo = W_out[t * 256 + sub * 64 + c * 16 + l16];

        // copier: spin on the 2 flags of its source column-group
        if (cs >= 1) {
            if (t > 0) {
                const int fb = pbid * 8 + c_src * 2;
                while (ATL(&flags[fb]) < t || ATL(&flags[fb + 1]) < t)
                    __builtin_amdgcn_s_sleep(1);
                asm volatile("" ::: "memory");
            }
            const unsigned long long* pt = gb64 + (pbid * 2 + rp) * 256;
            unsigned long long d0 = ATL(pt + i0);
            unsigned long long d1 = ATL(pt + i0 + 1);
            union { unsigned long long u; unsigned short s[4]; } u0, u1;
            u0.u = d0; u1.u = d1;
            #pragma unroll
            for (int j = 0; j < 4; ++j) {
                reinterpret_cast<unsigned short*>(&h_full[cm0 + j][psub * 64 + chl])[0] = u0.s[j];
                reinterpret_cast<unsigned short*>(&h_full[cm0 + 4 + j][psub * 64 + chl])[0] = u1.s[j];
            }
        }
        __syncthreads();   // b_copy: h_full = full h_{t-1}

        // A fragments + MFMA (j=0,1 regs; j=2,3 LDS)
        half8 a[4];
        #pragma unroll
        for (int j = 0; j < 4; ++j)
            a[j] = *reinterpret_cast<const half8*>(&h_full[l16][(kh * 4 + j) * 32 + quad * 8]);
        f32x4 gacc[4];
        #pragma unroll
        for (int g = 0; g < 4; ++g) { f32x4 z = {0.f, 0.f, 0.f, 0.f}; gacc[g] = z; }
        #pragma unroll
        for (int jj = 0; jj < 2; ++jj)
            #pragma unroll
            for (int g = 0; g < 4; ++g) {
                int i = g * 2 + jj;
                half8 wv = __builtin_bit_cast(half8,
                    make_uint4(wr_[i][0], wr_[i][1], wr_[i][2], wr_[i][3]));
                gacc[g] = mfma16(a[jj], wv, gacc[g]);
            }
        #pragma unroll
        for (int jj = 0; jj < 2; ++jj)
            #pragma unroll
            for (int g = 0; g < 4; ++g)
                gacc[g] = mfma16(a[2 + jj],
                                 wl8[(((c * 4 + g) * 4) + kh * 2 + jj) * 64 + lane], gacc[g]);

        // pacc: write my OTHER two rows (roth = (1-kh)*2 + rr)
        #pragma unroll
        for (int g = 0; g < 4; ++g) {
            f32x2 v; v.x = gacc[g][(1 - kh) * 2 + 0]; v.y = gacc[g][(1 - kh) * 2 + 1];
            *reinterpret_cast<f32x2*>(&pacc1[c][kh][g][l16][quad * 2]) = v;
        }
        __syncthreads();   // b1: pacc exchanged; all A-reads drained

        // nonlin for my rows r_own = kh*2 + rr (batches m = quad*4 + r_own)
        {
            f32x2 p[4];
            #pragma unroll
            for (int g = 0; g < 4; ++g)
                p[g] = *reinterpret_cast<const f32x2*>(&pacc1[c][1 - kh][g][l16][quad * 2]);
            const int hl = c * 16 + l16;
            const int hk = sub * 64 + hl;
            union { unsigned int u; unsigned short s[2]; } hp;
            #pragma unroll
            for (int rr = 0; rr < 2; ++rr) {
                int ro = kh * 2 + rr;
                float pg[4] = { rr ? p[0].y : p[0].x, rr ? p[1].y : p[1].x,
                                rr ? p[2].y : p[2].x, rr ? p[3].y : p[3].x };
                float gi = gacc[0][ro] + pg[0] + (tsv[rr] * wih[0] + bias[0]);
                float gf = gacc[1][ro] + pg[1] + (tsv[rr] * wih[1] + bias[1]);
                float gg = gacc[2][ro] + pg[2] + (tsv[rr] * wih[2] + bias[2]);
                float go = gacc[3][ro] + pg[3] + (tsv[rr] * wih[3] + bias[3]);
                float I = __builtin_amdgcn_rcpf(1.0f + __builtin_amdgcn_exp2f(gi));
                float F = __builtin_amdgcn_rcpf(1.0f + __builtin_amdgcn_exp2f(gf));
                float G = 1.0f - 2.0f * __builtin_amdgcn_rcpf(1.0f + __builtin_amdgcn_exp2f(gg));
                float O = __builtin_amdgcn_rcpf(1.0f + __builtin_amdgcn_exp2f(go));
                float cn = F * cst[rr] + I * G;
                cst[rr] = cn;
                float tc = 1.0f - 2.0f * __builtin_amdgcn_rcpf(
                               1.0f + __builtin_amdgcn_exp2f(2.0f * kLog2e * cn));
                float hv = O * tc;
                oacc[rr] += hv * wo;
                _Float16 h16 = (_Float16)hv;
                hp.s[rr] = __builtin_bit_cast(unsigned short, h16);
                h_full[quad * 4 + ro][hk] = h16;    // own-sub LDS copy for t+1
            }
            // publish u32 ([hl][m] tile, m = quad*4 + kh*2 contiguous pair)
            ATS((unsigned int*)myt[wpar] + (hl * 8 + quad * 2 + kh), hp.u);
            asm volatile("s_waitcnt vmcnt(0)" ::: "memory");
            if (lane == 0) ATS(&flags[bid * 8 + c * 2 + kh], t + 1);
        }
        // no end barrier (r13-proven): pacc(t+1) writes gated by b_copy(t+1);
        // h_full scatter(t+1) after b1(t) which drained all A-reads(t).
    }

    // ---- output partials: reduce over l16 (cols); both kh waves fill red ----
    #pragma unroll
    for (int rr = 0; rr < 2; ++rr) {
        float v = oacc[rr];
        v += __shfl_xor(v, 1, 64);
        v += __shfl_xor(v, 2, 64);
        v += __shfl_xor(v, 4, 64);
        v += __shfl_xor(v, 8, 64);
        if (l16 == 0) red[c][quad * 4 + kh * 2 + rr] = v;
    }
    __syncthreads();
    if (tid < 16) {
        float s = 0.f;
        #pragma unroll
        for (int cc = 0; cc < 4; ++cc) s += red[cc][tid];
        pbuf[bid * 16 + tid] = s;
    }
}

__global__ void finalize(const float* __restrict__ pbuf,
                         const float* __restrict__ b_out,
                         float* __restrict__ out)
{
    int b = blockIdx.x * blockDim.x + threadIdx.x;   // 0..511
    int grp = b >> 4, m = b & 15;
    float s = b_out[0];
    #pragma unroll
    for (int s4 = 0; s4 < 4; ++s4) s += pbuf[((grp * 4 + s4) * 16) + m];
    out[b] = s;
}

extern "C" void kernel_launch(void* const* d_in, const int* in_sizes, int n_in,
                              void* d_out, int out_size, void* d_ws, size_t ws_size,
                              hipStream_t stream) {
    const float* ts    = (const float*)d_in[0];
    const float* W_ih  = (const float*)d_in[1];
    const float* W_hh  = (const float*)d_in[2];
    const float* b_ih  = (const float*)d_in[3];
    const float* b_hh  = (const float*)d_in[4];
    const float* W_out = (const float*)d_in[5];
    const float* b_out = (const float*)d_in[6];

    char* wsb = (char*)d_ws;
    _Float16*       wfrag = (_Float16*)wsb;
    unsigned short* gb    = (unsigned short*)(wsb + 524288);
    int*            flags = (int*)(wsb + 1048576);
    float*          pbuf  = (float*)(wsb + 1052672);

    // zero gbuf (t=0 reads parity-1 tiles as h_{-1}=0) + flags + pbuf
    hipMemsetAsync(wsb + 524288, 0, 524288 + 4096 + 8192, stream);
    prep_weights<<<128, 256, 0, stream>>>(W_hh, wfrag);
    lstm_main<<<128, 512, 0, stream>>>(ts, W_ih, b_ih, b_hh, W_out,
                                       wfrag, gb, flags, pbuf);
    finalize<<<1, 512, 0, stream>>>(pbuf, b_out, (float*)d_out);
}

// Round 15
// 1304.903 us; speedup vs baseline: 1.6506x; 1.1146x over previous
//
#include <hip/hip_runtime.h>

// LSTM B=512, T=512, H=256. Round 15 = r14 on 256 blocks (all CUs).
// r14: 128 blocks -> half the GPU idle; step 6685 cyc dominated by LLC chain
// (~2500-3500 incl. spin-VALU) + LDS ~1500. Here: 64 groups x 4 subs = 256
// blocks, 8 batches each. Tile 1 KB (copier 1 u64/thread, scatter halves),
// pacc/publish/nonlin halve; weights (32-dword reg tier -- PROVEN to hold at
// VGPR=88 in r14 -- + 64 KB wlds) unchanged; MFMA M-rows 8..15 run on zeros.
// Protocol identical to r13/r14: per-(c,kh) flags, parity tiles, no end barrier.
// MFMA f32_16x16x32_f16: A=h[m=l16][k=quad*8+j], B=W[k][n=l16], D[m=quad*4+r][n].
// Weights prescaled by -log2e (i,f,o) / +2log2e (g).

typedef _Float16 half8 __attribute__((ext_vector_type(8)));
typedef float f32x4 __attribute__((ext_vector_type(4)));
typedef float f32x2 __attribute__((ext_vector_type(2)));

constexpr int kT = 512;
constexpr int kHF = 264;   // h_full row stride (halves)
constexpr float kLog2e = 1.44269504088896340736f;

#define ATL(p)    __hip_atomic_load((p), __ATOMIC_RELAXED, __HIP_MEMORY_SCOPE_AGENT)
#define ATS(p, v) __hip_atomic_store((p), (v), __ATOMIC_RELAXED, __HIP_MEMORY_SCOPE_AGENT)

// ws layout (bytes):
//   [0, 524288)         weight fragments fp16: frag (sub,c,g,kt) at half8 idx
//                       (sub*128 + (c*4+g)*8 + kt)*64 + lane
//   [524288, 1048576)   gbuf: tile(bid,par) 1 KB at +(bid*2+par)*1024,
//                       layout [hl 0..63][m 0..7] u16
//   [1048576, 1056768)  flags int[256][8]  (bid, c*2+kh)
//   [1056768, 1064960)  pbuf float[256][8]
__global__ void prep_weights(const float* __restrict__ W_hh, _Float16* __restrict__ ws)
{
    int gid = blockIdx.x * blockDim.x + threadIdx.x;  // 0..32767, one half8 each
    int lane = gid & 63;
    int f = (gid >> 6) & 127;
    int sub = gid >> 13;
    int kt = f & 7, g = (f >> 3) & 3, c = f >> 5;
    int R = g * 256 + sub * 64 + c * 16 + (lane & 15);
    int k = kt * 32 + (lane >> 4) * 8;
    float s = (g == 2) ? 2.0f * kLog2e : -kLog2e;
    const float* src = W_hh + R * 256 + k;
    half8 v;
    #pragma unroll
    for (int j = 0; j < 8; ++j) v[j] = (_Float16)(src[j] * s);
    reinterpret_cast<half8*>(ws)[gid] = v;
}

__device__ __forceinline__ f32x4 mfma16(half8 a, half8 b, f32x4 c) {
    return __builtin_amdgcn_mfma_f32_16x16x32_f16(a, b, c, 0, 0, 0);
}

__global__ __launch_bounds__(512, 2)
void lstm_main(const float* __restrict__ ts,
               const float* __restrict__ W_ih,
               const float* __restrict__ b_ih,
               const float* __restrict__ b_hh,
               const float* __restrict__ W_out,
               const _Float16* __restrict__ wfrag,
               unsigned short* __restrict__ gb,
               int* __restrict__ flags,
               float* __restrict__ pbuf)
{
    __shared__ __align__(16) _Float16 wlds[32768];        // 64 KB: jj=2,3 frags
    __shared__ __align__(16) _Float16 h_full[16][kHF];    // 8448 B (rows 8..15 stay 0)
    __shared__ __align__(16) float pacc1[4][2][4][16][10];// 20480 B
    __shared__ float red[4][8];

    const int tid  = threadIdx.x;
    const int w    = tid >> 6;
    const int lane = tid & 63;
    const int l16  = lane & 15;
    const int quad = lane >> 4;
    const int bid  = blockIdx.x;
    const int sub  = bid & 3;
    const int grp  = bid >> 2;     // 0..63
    const int b0   = grp * 8;
    const int c    = w & 3;        // column-group 0..3
    const int kh   = w >> 2;       // K-half 0..1

    const half8* wf8 = reinterpret_cast<const half8*>(wfrag) + sub * 8192;
    half8* wl8 = reinterpret_cast<half8*>(wlds);

    // stage LDS weight tier: frags (c,g,kh,jj) = src kt kh*4+2+jj
    for (int i = tid; i < 4096; i += 512) {
        int f = i >> 6, ln = i & 63;
        int jj = f & 1, kh_ = (f >> 1) & 1, g_ = (f >> 2) & 3, c_ = f >> 4;
        wl8[i] = wf8[(((c_ * 4 + g_) * 8) + kh_ * 4 + 2 + jj) * 64 + ln];
    }
    for (int i = tid; i < 16 * kHF; i += 512) (&h_full[0][0])[i] = (_Float16)0.0f;

    // ---- register weight tier: frags jj=0,1 (kt = kh*4 + jj), 32 VGPRs (r14-proven) ----
    unsigned int wr_[8][4];
    #pragma unroll
    for (int g = 0; g < 4; ++g)
        #pragma unroll
        for (int jj = 0; jj < 2; ++jj) {
            uint4 v = *reinterpret_cast<const uint4*>(
                &wf8[(((c * 4 + g) * 8) + kh * 4 + jj) * 64 + lane]);
            int i = g * 2 + jj;
            wr_[i][0] = v.x; wr_[i][1] = v.y; wr_[i][2] = v.z; wr_[i][3] = v.w;
            asm volatile("" : "+v"(wr_[i][0]), "+v"(wr_[i][1]), "+v"(wr_[i][2]), "+v"(wr_[i][3]));
        }

    // per-col scalars
    float wih[4], bias[4];
    #pragma unroll
    for (int g = 0; g < 4; ++g) {
        int R = g * 256 + sub * 64 + c * 16 + l16;
        float s = (g == 2) ? 2.0f * kLog2e : -kLog2e;
        wih[g]  = W_ih[R] * s;
        bias[g] = (b_ih[R] + b_hh[R]) * s;
    }

    // copier mapping: tid>=128 copies 1 u64 (= 4 m's at one hl) of partner tile psub
    const int cs    = tid >> 7;            // 0 none; 1..3 partner offset
    const int psub  = (sub + cs) & 3;
    const int pbid  = (grp << 2) | psub;
    const int i0    = tid & 127;           // u64 index in 1 KB tile
    const int chl   = i0 >> 1;             // hl 0..63
    const int cm0   = (i0 & 1) * 4;        // m base 0 or 4
    const int c_src = chl >> 4;
    const unsigned long long* gb64 = reinterpret_cast<const unsigned long long*>(gb);
    unsigned short* myt[2] = { gb + (bid * 2 + 0) * 512, gb + (bid * 2 + 1) * 512 };

    float cst[2]  = {0.f, 0.f};
    float oacc[2] = {0.f, 0.f};

    __syncthreads();

    for (int t = 0; t < kT; ++t) {
        const int wpar = t & 1, rp = (t + 1) & 1;

        // in-loop re-pin (r14-proven at this budget)
        #pragma unroll
        for (int i = 0; i < 8; ++i)
            asm volatile("" : "+v"(wr_[i][0]), "+v"(wr_[i][1]), "+v"(wr_[i][2]), "+v"(wr_[i][3]));

        // nonlin VMEM prefetch (quads 0,1 only: m = quad*4 + kh*2 + rr <= 7)
        float tsv[2] = {0.f, 0.f};
        float wo = 0.f;
        if (quad < 2) {
            #pragma unroll
            for (int rr = 0; rr < 2; ++rr)
                tsv[rr] = ts[(b0 + quad * 4 + kh * 2 + rr) * kT + t];
            wo = W_out[t * 256 + sub * 64 + c * 16 + l16];
        }

        // copier: spin on the 2 flags of its source column-group, then 1 u64 read
        if (cs >= 1) {
            if (t > 0) {
                const int fb = pbid * 8 + c_src * 2;
                while (ATL(&flags[fb]) < t || ATL(&flags[fb + 1]) < t)
                    __builtin_amdgcn_s_sleep(1);
                asm volatile("" ::: "memory");
            }
            const unsigned long long* pt = gb64 + (pbid * 2 + rp) * 128;
            unsigned long long d0 = ATL(pt + i0);
            union { unsigned long long u; unsigned short s[4]; } u0;
            u0.u = d0;
            #pragma unroll
            for (int j = 0; j < 4; ++j)
                reinterpret_cast<unsigned short*>(&h_full[cm0 + j][psub * 64 + chl])[0] = u0.s[j];
        }
        __syncthreads();   // b_copy: h_full rows 0..7 = full h_{t-1}

        // A fragments + MFMA (jj=0,1 regs; jj=2,3 LDS)
        half8 a[4];
        #pragma unroll
        for (int j = 0; j < 4; ++j)
            a[j] = *reinterpret_cast<const half8*>(&h_full[l16][(kh * 4 + j) * 32 + quad * 8]);
        f32x4 gacc[4];
        #pragma unroll
        for (int g = 0; g < 4; ++g) { f32x4 z = {0.f, 0.f, 0.f, 0.f}; gacc[g] = z; }
        #pragma unroll
        for (int jj = 0; jj < 2; ++jj)
            #pragma unroll
            for (int g = 0; g < 4; ++g) {
                int i = g * 2 + jj;
                half8 wv = __builtin_bit_cast(half8,
                    make_uint4(wr_[i][0], wr_[i][1], wr_[i][2], wr_[i][3]));
                gacc[g] = mfma16(a[jj], wv, gacc[g]);
            }
        #pragma unroll
        for (int jj = 0; jj < 2; ++jj)
            #pragma unroll
            for (int g = 0; g < 4; ++g)
                gacc[g] = mfma16(a[2 + jj],
                                 wl8[(((c * 4 + g) * 4) + kh * 2 + jj) * 64 + lane], gacc[g]);

        // pacc: exchange my OTHER two rows with the partner kh wave
        #pragma unroll
        for (int g = 0; g < 4; ++g) {
            f32x2 v; v.x = gacc[g][(1 - kh) * 2 + 0]; v.y = gacc[g][(1 - kh) * 2 + 1];
            *reinterpret_cast<f32x2*>(&pacc1[c][kh][g][l16][quad * 2]) = v;
        }
        __syncthreads();   // b1: pacc exchanged; all A-reads drained

        // nonlin (quads 0,1): rows m = quad*4 + kh*2 + rr
        if (quad < 2) {
            f32x2 p[4];
            #pragma unroll
            for (int g = 0; g < 4; ++g)
                p[g] = *reinterpret_cast<const f32x2*>(&pacc1[c][1 - kh][g][l16][quad * 2]);
            const int hl = c * 16 + l16;
            const int hk = sub * 64 + hl;
            union { unsigned int u; unsigned short s[2]; } hp;
            #pragma unroll
            for (int rr = 0; rr < 2; ++rr) {
                int ro = kh * 2 + rr;
                float pg[4] = { rr ? p[0].y : p[0].x, rr ? p[1].y : p[1].x,
                                rr ? p[2].y : p[2].x, rr ? p[3].y : p[3].x };
                float gi = gacc[0][ro] + pg[0] + (tsv[rr] * wih[0] + bias[0]);
                float gf = gacc[1][ro] + pg[1] + (tsv[rr] * wih[1] + bias[1]);
                float gg = gacc[2][ro] + pg[2] + (tsv[rr] * wih[2] + bias[2]);
                float go = gacc[3][ro] + pg[3] + (tsv[rr] * wih[3] + bias[3]);
                float I = __builtin_amdgcn_rcpf(1.0f + __builtin_amdgcn_exp2f(gi));
                float F = __builtin_amdgcn_rcpf(1.0f + __builtin_amdgcn_exp2f(gf));
                float G = 1.0f - 2.0f * __builtin_amdgcn_rcpf(1.0f + __builtin_amdgcn_exp2f(gg));
                float O = __builtin_amdgcn_rcpf(1.0f + __builtin_amdgcn_exp2f(go));
                float cn = F * cst[rr] + I * G;
                cst[rr] = cn;
                float tc = 1.0f - 2.0f * __builtin_amdgcn_rcpf(
                               1.0f + __builtin_amdgcn_exp2f(2.0f * kLog2e * cn));
                float hv = O * tc;
                oacc[rr] += hv * wo;
                _Float16 h16 = (_Float16)hv;
                hp.s[rr] = __builtin_bit_cast(unsigned short, h16);
                h_full[quad * 4 + ro][hk] = h16;    // own-sub LDS copy for t+1
            }
            // publish u32 at [hl][m-pair]: pair index = quad*2 + kh
            ATS((unsigned int*)myt[wpar] + (hl * 4 + quad * 2 + kh), hp.u);
        }
        asm volatile("s_waitcnt vmcnt(0)" ::: "memory");
        if (lane == 0) ATS(&flags[bid * 8 + c * 2 + kh], t + 1);
        // no end barrier (r13/r14-proven)
    }

    // ---- output partials: reduce over l16 (cols); quads 0,1 fill red ----
    #pragma unroll
    for (int rr = 0; rr < 2; ++rr) {
        float v = oacc[rr];
        v += __shfl_xor(v, 1, 64);
        v += __shfl_xor(v, 2, 64);
        v += __shfl_xor(v, 4, 64);
        v += __shfl_xor(v, 8, 64);
        if (l16 == 0 && quad < 2) red[c][quad * 4 + kh * 2 + rr] = v;
    }
    __syncthreads();
    if (tid < 8) {
        float s = 0.f;
        #pragma unroll
        for (int cc = 0; cc < 4; ++cc) s += red[cc][tid];
        pbuf[bid * 8 + tid] = s;
    }
}

__global__ void finalize(const float* __restrict__ pbuf,
                         const float* __restrict__ b_out,
                         float* __restrict__ out)
{
    int b = blockIdx.x * blockDim.x + threadIdx.x;   // 0..511
    int grp = b >> 3, m = b & 7;
    float s = b_out[0];
    #pragma unroll
    for (int s4 = 0; s4 < 4; ++s4) s += pbuf[((grp * 4 + s4) * 8) + m];
    out[b] = s;
}

extern "C" void kernel_launch(void* const* d_in, const int* in_sizes, int n_in,
                              void* d_out, int out_size, void* d_ws, size_t ws_size,
                              hipStream_t stream) {
    const float* ts    = (const float*)d_in[0];
    const float* W_ih  = (const float*)d_in[1];
    const float* W_hh  = (const float*)d_in[2];
    const float* b_ih  = (const float*)d_in[3];
    const float* b_hh  = (const float*)d_in[4];
    const float* W_out = (const float*)d_in[5];
    const float* b_out = (const float*)d_in[6];

    char* wsb = (char*)d_ws;
    _Float16*       wfrag = (_Float16*)wsb;
    unsigned short* gb    = (unsigned short*)(wsb + 524288);
    int*            flags = (int*)(wsb + 1048576);
    float*          pbuf  = (float*)(wsb + 1056768);

    // zero gbuf (t=0 reads parity-1 tiles as h_{-1}=0) + flags + pbuf
    hipMemsetAsync(wsb + 524288, 0, 524288 + 8192 + 8192, stream);
    prep_weights<<<128, 256, 0, stream>>>(W_hh, wfrag);
    lstm_main<<<256, 512, 0, stream>>>(ts, W_ih, b_ih, b_hh, W_out,
                                       wfrag, gb, flags, pbuf);
    finalize<<<1, 512, 0, stream>>>(pbuf, b_out, (float*)d_out);
}

// Round 16
// 997.529 us; speedup vs baseline: 2.1592x; 1.3081x over previous
//
#include <hip/hip_runtime.h>

// LSTM B=512, T=512, H=256. Round 16 = r15 + fused {seq,data} u64 records.
// r15 wall: serial LLC handshake ~2500 cyc (publish -> vmcnt drain -> flag
// store RT -> flag poll RT -> tile read RT). Fix: each published h-pair is ONE
// atomic u64 {hi32 = seq = t+1, lo32 = 2 x fp16}. Consumer spins on its own
// records until seq == t -> drain, flag store, flag poll, and the separate
// data-read RT all deleted; the poll IS the data read.
// Safety (r10 induction, now self-tagged): parity slot written at steps t-1
// (seq t) and t+1 (seq t+2); partner's t+1 publish is gated on OUR step-t
// publish, which is barrier-ordered after OUR copier reads of its seq-t
// records -> no overwrite-before-read, and a spinner for seq==t cannot be
// skipped past. Monotone seq == exact match test.
// 256 blocks x 512 thr; grp=bid>>2 owns 8 batches; sub owns 64 h-cols;
// reg tier 32 VGPR (r14/r15-proven) + 64 KB wlds. Protocol otherwise r15.
// MFMA f32_16x16x32_f16: A=h[m=l16][k=quad*8+j], B=W[k][n=l16], D[m=quad*4+r][n].
// Weights prescaled by -log2e (i,f,o) / +2log2e (g).

typedef _Float16 half8 __attribute__((ext_vector_type(8)));
typedef float f32x4 __attribute__((ext_vector_type(4)));
typedef float f32x2 __attribute__((ext_vector_type(2)));

constexpr int kT = 512;
constexpr int kHF = 264;   // h_full row stride (halves)
constexpr float kLog2e = 1.44269504088896340736f;

#define ATL(p)    __hip_atomic_load((p), __ATOMIC_RELAXED, __HIP_MEMORY_SCOPE_AGENT)
#define ATS(p, v) __hip_atomic_store((p), (v), __ATOMIC_RELAXED, __HIP_MEMORY_SCOPE_AGENT)

// ws layout (bytes):
//   [0, 524288)          weight fragments fp16: frag (sub,c,g,kt) at half8 idx
//                        (sub*128 + (c*4+g)*8 + kt)*64 + lane
//   [524288, 1572864)    gbuf: tile(bid,par) = 256 u64 records at
//                        +(bid*2+par)*2048; record ri = hl*4 + pair,
//                        pair = quad*2+kh, m = quad*4 + kh*2 + rr
//   [1572864, 1581056)   pbuf float[256][8]
__global__ void prep_weights(const float* __restrict__ W_hh, _Float16* __restrict__ ws)
{
    int gid = blockIdx.x * blockDim.x + threadIdx.x;  // 0..32767, one half8 each
    int lane = gid & 63;
    int f = (gid >> 6) & 127;
    int sub = gid >> 13;
    int kt = f & 7, g = (f >> 3) & 3, c = f >> 5;
    int R = g * 256 + sub * 64 + c * 16 + (lane & 15);
    int k = kt * 32 + (lane >> 4) * 8;
    float s = (g == 2) ? 2.0f * kLog2e : -kLog2e;
    const float* src = W_hh + R * 256 + k;
    half8 v;
    #pragma unroll
    for (int j = 0; j < 8; ++j) v[j] = (_Float16)(src[j] * s);
    reinterpret_cast<half8*>(ws)[gid] = v;
}

__device__ __forceinline__ f32x4 mfma16(half8 a, half8 b, f32x4 c) {
    return __builtin_amdgcn_mfma_f32_16x16x32_f16(a, b, c, 0, 0, 0);
}

__global__ __launch_bounds__(512, 2)
void lstm_main(const float* __restrict__ ts,
               const float* __restrict__ W_ih,
               const float* __restrict__ b_ih,
               const float* __restrict__ b_hh,
               const float* __restrict__ W_out,
               const _Float16* __restrict__ wfrag,
               unsigned long long* __restrict__ gb64,
               float* __restrict__ pbuf)
{
    __shared__ __align__(16) _Float16 wlds[32768];        // 64 KB: jj=2,3 frags
    __shared__ __align__(16) _Float16 h_full[16][kHF];    // 8448 B (rows 8..15 stay 0)
    __shared__ __align__(16) float pacc1[4][2][4][16][10];// 20480 B
    __shared__ float red[4][8];

    const int tid  = threadIdx.x;
    const int w    = tid >> 6;
    const int lane = tid & 63;
    const int l16  = lane & 15;
    const int quad = lane >> 4;
    const int bid  = blockIdx.x;
    const int sub  = bid & 3;
    const int grp  = bid >> 2;     // 0..63
    const int b0   = grp * 8;
    const int c    = w & 3;        // column-group 0..3
    const int kh   = w >> 2;       // K-half 0..1

    const half8* wf8 = reinterpret_cast<const half8*>(wfrag) + sub * 8192;
    half8* wl8 = reinterpret_cast<half8*>(wlds);

    // stage LDS weight tier: frags (c,g,kh,jj) = src kt kh*4+2+jj
    for (int i = tid; i < 4096; i += 512) {
        int f = i >> 6, ln = i & 63;
        int jj = f & 1, kh_ = (f >> 1) & 1, g_ = (f >> 2) & 3, c_ = f >> 4;
        wl8[i] = wf8[(((c_ * 4 + g_) * 8) + kh_ * 4 + 2 + jj) * 64 + ln];
    }
    for (int i = tid; i < 16 * kHF; i += 512) (&h_full[0][0])[i] = (_Float16)0.0f;

    // ---- register weight tier: frags jj=0,1 (kt = kh*4 + jj), 32 VGPRs ----
    unsigned int wr_[8][4];
    #pragma unroll
    for (int g = 0; g < 4; ++g)
        #pragma unroll
        for (int jj = 0; jj < 2; ++jj) {
            uint4 v = *reinterpret_cast<const uint4*>(
                &wf8[(((c * 4 + g) * 8) + kh * 4 + jj) * 64 + lane]);
            int i = g * 2 + jj;
            wr_[i][0] = v.x; wr_[i][1] = v.y; wr_[i][2] = v.z; wr_[i][3] = v.w;
            asm volatile("" : "+v"(wr_[i][0]), "+v"(wr_[i][1]), "+v"(wr_[i][2]), "+v"(wr_[i][3]));
        }

    // per-col scalars
    float wih[4], bias[4];
    #pragma unroll
    for (int g = 0; g < 4; ++g) {
        int R = g * 256 + sub * 64 + c * 16 + l16;
        float s = (g == 2) ? 2.0f * kLog2e : -kLog2e;
        wih[g]  = W_ih[R] * s;
        bias[g] = (b_ih[R] + b_hh[R]) * s;
    }

    // copier mapping: tid>=128 handles 2 consecutive records of partner tile psub
    const int cs    = tid >> 7;            // 0 none; 1..3 partner offset
    const int psub  = (sub + cs) & 3;
    const int pbid  = (grp << 2) | psub;
    const int i0    = tid & 127;           // record-pair index
    const int chl   = i0 >> 1;             // hl 0..63
    const int cm0   = (i0 & 1) * 4;        // m base 0 or 4
    unsigned long long* myt[2] = { gb64 + (bid * 2 + 0) * 256, gb64 + (bid * 2 + 1) * 256 };

    float cst[2]  = {0.f, 0.f};
    float oacc[2] = {0.f, 0.f};

    __syncthreads();

    for (int t = 0; t < kT; ++t) {
        const int wpar = t & 1, rp = (t + 1) & 1;

        // in-loop re-pin (r14/r15-proven at this budget)
        #pragma unroll
        for (int i = 0; i < 8; ++i)
            asm volatile("" : "+v"(wr_[i][0]), "+v"(wr_[i][1]), "+v"(wr_[i][2]), "+v"(wr_[i][3]));

        // nonlin VMEM prefetch (quads 0,1 only)
        float tsv[2] = {0.f, 0.f};
        float wo = 0.f;
        if (quad < 2) {
            #pragma unroll
            for (int rr = 0; rr < 2; ++rr)
                tsv[rr] = ts[(b0 + quad * 4 + kh * 2 + rr) * kT + t];
            wo = W_out[t * 256 + sub * 64 + c * 16 + l16];
        }

        // copier: spin directly on its 2 self-tagged records (seq == t)
        if (cs >= 1) {
            const unsigned long long* pt = gb64 + (pbid * 2 + rp) * 256 + i0 * 2;
            unsigned long long v0, v1;
            const unsigned long long want = (unsigned long long)t;
            for (;;) {
                v0 = ATL(pt);
                v1 = ATL(pt + 1);
                if ((v0 >> 32) == want && (v1 >> 32) == want) break;
                __builtin_amdgcn_s_sleep(1);
            }
            union { unsigned int u; unsigned short s[2]; } a0, a1;
            a0.u = (unsigned int)v0; a1.u = (unsigned int)v1;
            reinterpret_cast<unsigned short*>(&h_full[cm0 + 0][psub * 64 + chl])[0] = a0.s[0];
            reinterpret_cast<unsigned short*>(&h_full[cm0 + 1][psub * 64 + chl])[0] = a0.s[1];
            reinterpret_cast<unsigned short*>(&h_full[cm0 + 2][psub * 64 + chl])[0] = a1.s[0];
            reinterpret_cast<unsigned short*>(&h_full[cm0 + 3][psub * 64 + chl])[0] = a1.s[1];
        }
        __syncthreads();   // b_copy: h_full rows 0..7 = full h_{t-1}

        // A fragments + MFMA (jj=0,1 regs; jj=2,3 LDS)
        half8 a[4];
        #pragma unroll
        for (int j = 0; j < 4; ++j)
            a[j] = *reinterpret_cast<const half8*>(&h_full[l16][(kh * 4 + j) * 32 + quad * 8]);
        f32x4 gacc[4];
        #pragma unroll
        for (int g = 0; g < 4; ++g) { f32x4 z = {0.f, 0.f, 0.f, 0.f}; gacc[g] = z; }
        #pragma unroll
        for (int jj = 0; jj < 2; ++jj)
            #pragma unroll
            for (int g = 0; g < 4; ++g) {
                int i = g * 2 + jj;
                half8 wv = __builtin_bit_cast(half8,
                    make_uint4(wr_[i][0], wr_[i][1], wr_[i][2], wr_[i][3]));
                gacc[g] = mfma16(a[jj], wv, gacc[g]);
            }
        #pragma unroll
        for (int jj = 0; jj < 2; ++jj)
            #pragma unroll
            for (int g = 0; g < 4; ++g)
                gacc[g] = mfma16(a[2 + jj],
                                 wl8[(((c * 4 + g) * 4) + kh * 2 + jj) * 64 + lane], gacc[g]);

        // pacc: exchange my OTHER two rows with the partner kh wave
        #pragma unroll
        for (int g = 0; g < 4; ++g) {
            f32x2 v; v.x = gacc[g][(1 - kh) * 2 + 0]; v.y = gacc[g][(1 - kh) * 2 + 1];
            *reinterpret_cast<f32x2*>(&pacc1[c][kh][g][l16][quad * 2]) = v;
        }
        __syncthreads();   // b1: pacc exchanged; all A-reads drained

        // nonlin (quads 0,1): rows m = quad*4 + kh*2 + rr
        if (quad < 2) {
            f32x2 p[4];
            #pragma unroll
            for (int g = 0; g < 4; ++g)
                p[g] = *reinterpret_cast<const f32x2*>(&pacc1[c][1 - kh][g][l16][quad * 2]);
            const int hl = c * 16 + l16;
            const int hk = sub * 64 + hl;
            union { unsigned int u; unsigned short s[2]; } hp;
            #pragma unroll
            for (int rr = 0; rr < 2; ++rr) {
                int ro = kh * 2 + rr;
                float pg[4] = { rr ? p[0].y : p[0].x, rr ? p[1].y : p[1].x,
                                rr ? p[2].y : p[2].x, rr ? p[3].y : p[3].x };
                float gi = gacc[0][ro] + pg[0] + (tsv[rr] * wih[0] + bias[0]);
                float gf = gacc[1][ro] + pg[1] + (tsv[rr] * wih[1] + bias[1]);
                float gg = gacc[2][ro] + pg[2] + (tsv[rr] * wih[2] + bias[2]);
                float go = gacc[3][ro] + pg[3] + (tsv[rr] * wih[3] + bias[3]);
                float I = __builtin_amdgcn_rcpf(1.0f + __builtin_amdgcn_exp2f(gi));
                float F = __builtin_amdgcn_rcpf(1.0f + __builtin_amdgcn_exp2f(gf));
                float G = 1.0f - 2.0f * __builtin_amdgcn_rcpf(1.0f + __builtin_amdgcn_exp2f(gg));
                float O = __builtin_amdgcn_rcpf(1.0f + __builtin_amdgcn_exp2f(go));
                float cn = F * cst[rr] + I * G;
                cst[rr] = cn;
                float tc = 1.0f - 2.0f * __builtin_amdgcn_rcpf(
                               1.0f + __builtin_amdgcn_exp2f(2.0f * kLog2e * cn));
                float hv = O * tc;
                oacc[rr] += hv * wo;
                _Float16 h16 = (_Float16)hv;
                hp.s[rr] = __builtin_bit_cast(unsigned short, h16);
                h_full[quad * 4 + ro][hk] = h16;    // own-sub LDS copy for t+1
            }
            // fused publish: one u64 {seq = t+1, 2 x fp16} — no drain, no flag
            unsigned long long rec = ((unsigned long long)(t + 1) << 32) | hp.u;
            ATS(myt[wpar] + (hl * 4 + quad * 2 + kh), rec);
        }
        // no end barrier (r13..r15-proven)
    }

    // ---- output partials: reduce over l16 (cols); quads 0,1 fill red ----
    #pragma unroll
    for (int rr = 0; rr < 2; ++rr) {
        float v = oacc[rr];
        v += __shfl_xor(v, 1, 64);
        v += __shfl_xor(v, 2, 64);
        v += __shfl_xor(v, 4, 64);
        v += __shfl_xor(v, 8, 64);
        if (l16 == 0 && quad < 2) red[c][quad * 4 + kh * 2 + rr] = v;
    }
    __syncthreads();
    if (tid < 8) {
        float s = 0.f;
        #pragma unroll
        for (int cc = 0; cc < 4; ++cc) s += red[cc][tid];
        pbuf[bid * 8 + tid] = s;
    }
}

__global__ void finalize(const float* __restrict__ pbuf,
                         const float* __restrict__ b_out,
                         float* __restrict__ out)
{
    int b = blockIdx.x * blockDim.x + threadIdx.x;   // 0..511
    int grp = b >> 3, m = b & 7;
    float s = b_out[0];
    #pragma unroll
    for (int s4 = 0; s4 < 4; ++s4) s += pbuf[((grp * 4 + s4) * 8) + m];
    out[b] = s;
}

extern "C" void kernel_launch(void* const* d_in, const int* in_sizes, int n_in,
                              void* d_out, int out_size, void* d_ws, size_t ws_size,
                              hipStream_t stream) {
    const float* ts    = (const float*)d_in[0];
    const float* W_ih  = (const float*)d_in[1];
    const float* W_hh  = (const float*)d_in[2];
    const float* b_ih  = (const float*)d_in[3];
    const float* b_hh  = (const float*)d_in[4];
    const float* W_out = (const float*)d_in[5];
    const float* b_out = (const float*)d_in[6];

    char* wsb = (char*)d_ws;
    _Float16*           wfrag = (_Float16*)wsb;
    unsigned long long* gb64  = (unsigned long long*)(wsb + 524288);
    float*              pbuf  = (float*)(wsb + 1572864);

    // zero gbuf (t=0 spins expect seq 0 / zero data on parity-1) + pbuf
    hipMemsetAsync(wsb + 524288, 0, 1048576 + 8192, stream);
    prep_weights<<<128, 256, 0, stream>>>(W_hh, wfrag);
    lstm_main<<<256, 512, 0, stream>>>(ts, W_ih, b_ih, b_hh, W_out,
                                       wfrag, gb64, pbuf);
    finalize<<<1, 512, 0, stream>>>(pbuf, b_out, (float*)d_out);
}